// Round 7
// baseline (629.505 us; speedup 1.0000x reference)
//
#include <hip/hip_runtime.h>
#include <stdint.h>

#define B_DIM 4
#define S_DIM 2048
#define D_DIM 2048
#define H_DIM 16
#define M_ROWS (B_DIM * S_DIM)   // 8192
#define CONCAT_LD 4096
#define NCHUNK 64
#define CHLEN (S_DIM / NCHUNK)   // 32

#define BM 128
#define BN 128
#define BK 64

typedef __attribute__((ext_vector_type(8))) __bf16 bf16x8;
typedef __attribute__((ext_vector_type(4))) float f32x4;

__device__ inline unsigned short f2bf(float f) {
  union { float f; unsigned u; } x; x.f = f;
  unsigned r = x.u + 0x7fffu + ((x.u >> 16) & 1u);
  return (unsigned short)(r >> 16);
}
__device__ inline float bf2f(unsigned short s) {
  union { unsigned u; float f; } x; x.u = ((unsigned)s) << 16;
  return x.f;
}
__device__ inline float bfLo(unsigned u) {
  union { unsigned x; float f; } c; c.x = u << 16; return c.f;
}
__device__ inline float bfHi(unsigned u) {
  union { unsigned x; float f; } c; c.x = u & 0xffff0000u; return c.f;
}

// ---- fused: x fp32 -> bf16 into concat[:,0:2048] AND logits = x @ W_att ----
__global__ __launch_bounds__(256) void xconv_logits_kernel(
    const float* __restrict__ x, const float* __restrict__ Watt,
    unsigned short* __restrict__ concat, float* __restrict__ logits) {
  int r0 = blockIdx.x * 4, t = threadIdx.x;
  float p[4][H_DIM];
#pragma unroll
  for (int r = 0; r < 4; ++r)
#pragma unroll
    for (int h = 0; h < H_DIM; ++h) p[r][h] = 0.f;
#pragma unroll
  for (int i = 0; i < 2; ++i) {
    int k = t * 4 + i * 1024;
    float4 xv[4];
#pragma unroll
    for (int r = 0; r < 4; ++r) {
      xv[r] = *(const float4*)(x + (size_t)(r0 + r) * D_DIM + k);
      ushort4 o;
      o.x = f2bf(xv[r].x); o.y = f2bf(xv[r].y); o.z = f2bf(xv[r].z); o.w = f2bf(xv[r].w);
      *(ushort4*)(concat + (size_t)(r0 + r) * CONCAT_LD + k) = o;
    }
#pragma unroll
    for (int kk = 0; kk < 4; ++kk) {
      const float* w = Watt + (size_t)(k + kk) * H_DIM;
      float wr[H_DIM];
#pragma unroll
      for (int h = 0; h < H_DIM; ++h) wr[h] = w[h];
#pragma unroll
      for (int r = 0; r < 4; ++r) {
        float xs = (kk == 0) ? xv[r].x : (kk == 1) ? xv[r].y : (kk == 2) ? xv[r].z : xv[r].w;
#pragma unroll
        for (int h = 0; h < H_DIM; ++h) p[r][h] += xs * wr[h];
      }
    }
  }
  __shared__ float red[4][4][H_DIM];
  int l = t & 63, w = t >> 6;
#pragma unroll
  for (int r = 0; r < 4; ++r)
#pragma unroll
    for (int h = 0; h < H_DIM; ++h) {
      float v = p[r][h];
      for (int off = 32; off; off >>= 1) v += __shfl_down(v, off);
      if (l == 0) red[w][r][h] = v;
    }
  __syncthreads();
  if (t < 64) {
    int r = t >> 4, h = t & 15;
    logits[(size_t)(r0 + r) * H_DIM + h] =
        red[0][r][h] + red[1][r][h] + red[2][r][h] + red[3][r][h];
  }
}

// ---- fused weight prep: 4 transposes (fp32->bf16^T, 64x32 tiles, ushort2
// writes) + 1 convert.  grid (64, 32, 5). ----
__global__ __launch_bounds__(256) void prep_kernel(
    const float* __restrict__ Wval, const float* __restrict__ ff1,
    const float* __restrict__ ff2, const float* __restrict__ Wop,
    unsigned short* __restrict__ wv_t, unsigned short* __restrict__ btff1,
    unsigned short* __restrict__ f1bT, unsigned short* __restrict__ ff2_t,
    unsigned short* __restrict__ wop_bf) {
  int z = blockIdx.z, t = threadIdx.x;
  if (z == 4) {
    size_t idx = (((size_t)blockIdx.y * 64 + blockIdx.x) * 256 + t) * 8;
    const float4 v0 = *(const float4*)(Wop + idx);
    const float4 v1 = *(const float4*)(Wop + idx + 4);
    ushort4 a, b;
    a.x = f2bf(v0.x); a.y = f2bf(v0.y); a.z = f2bf(v0.z); a.w = f2bf(v0.w);
    b.x = f2bf(v1.x); b.y = f2bf(v1.y); b.z = f2bf(v1.z); b.w = f2bf(v1.w);
    *(ushort4*)(wop_bf + idx) = a;
    *(ushort4*)(wop_bf + idx + 4) = b;
    return;
  }
  const float* src;
  unsigned short* dst;
  int ldd;
  if (z == 0)      { src = Wval;                        dst = wv_t;  ldd = 2048; }
  else if (z == 1) { src = ff1;                         dst = btff1; ldd = 4096; }
  else if (z == 2) { src = ff1 + (size_t)2048 * 2048;   dst = f1bT;  ldd = 2048; }
  else             { src = ff2;                         dst = ff2_t; ldd = 2048; }
  __shared__ float tile[64][33];
  int c0 = blockIdx.x * 32, r0 = blockIdx.y * 64;
  int tx = t & 31, ty = t >> 5;
#pragma unroll
  for (int i = 0; i < 64; i += 8)
    tile[ty + i][tx] = src[(size_t)(r0 + ty + i) * 2048 + c0 + tx];
  __syncthreads();
  int sx = t & 31, sy = t >> 5;
#pragma unroll
  for (int j = 0; j < 32; j += 8) {
    int c = c0 + sy + j;
    ushort2 o;
    o.x = f2bf(tile[sx * 2][sy + j]);
    o.y = f2bf(tile[sx * 2 + 1][sy + j]);
    *(ushort2*)(dst + (size_t)c * ldd + r0 + sx * 2) = o;
  }
}

// ---- per (b,h): max over s, then coef = w/(w*(s+1)+1e-30), w=exp((lg-mx)*T) ----
__global__ __launch_bounds__(256) void coef_kernel(
    const float* __restrict__ logits, const float* __restrict__ temp, float* __restrict__ coef) {
  int b = blockIdx.x >> 4, h = blockIdx.x & 15;
  int t = threadIdx.x;
  const float* lg = logits + (size_t)b * S_DIM * H_DIM + h;
  float mx = -1e30f;
  for (int s = t; s < S_DIM; s += 256) mx = fmaxf(mx, lg[(size_t)s * H_DIM]);
  for (int off = 32; off; off >>= 1) mx = fmaxf(mx, __shfl_down(mx, off));
  __shared__ float red[4];
  if ((t & 63) == 0) red[t >> 6] = mx;
  __syncthreads();
  mx = fmaxf(fmaxf(red[0], red[1]), fmaxf(red[2], red[3]));
  float T = temp[h];
  float* cf = coef + (size_t)b * S_DIM * H_DIM + h;
  for (int s = t; s < S_DIM; s += 256) {
    float w = expf((lg[(size_t)s * H_DIM] - mx) * T);
    cf[(size_t)s * H_DIM] = w / (w * (float)(s + 1) + 1e-30f);
  }
}

// ---- bias2 = vector @ F1b (+ ff1_b), partial over j-segments then reduce ----
__global__ __launch_bounds__(256) void bias2_partial_kernel(
    const float* __restrict__ vector, const float* __restrict__ ff1,
    float* __restrict__ part) {
  int n = blockIdx.x * 256 + threadIdx.x;
  int seg = blockIdx.y, b = blockIdx.z;
  const float* vr = vector + (size_t)b * 2048 + seg * 128;
  const float* fr = ff1 + (size_t)(2048 + seg * 128) * 2048 + n;
  float acc = 0.f;
#pragma unroll 8
  for (int j = 0; j < 128; ++j) acc += vr[j] * fr[(size_t)j * 2048];
  part[((size_t)seg * 4 + b) * 2048 + n] = acc;
}

__global__ __launch_bounds__(256) void bias2_reduce_kernel(
    const float* __restrict__ part, const float* __restrict__ ff1_b,
    float* __restrict__ bias2) {
  int n = blockIdx.x * 256 + threadIdx.x;
  int b = blockIdx.y;
  float acc = ff1_b[n];
#pragma unroll
  for (int s = 0; s < 16; ++s) acc += part[((size_t)s * 4 + b) * 2048 + n];
  bias2[(size_t)b * 2048 + n] = acc;
}

// ---- 128x128 GEMM (m97 structure) -- kept for the small 2048^3 Wc GEMM ----
template <int MODE>
__global__ __launch_bounds__(256) void gemm_bt_kernel(
    const unsigned short* __restrict__ A, int lda,
    const unsigned short* __restrict__ Bt, int ldb, int K,
    void* __restrict__ outp, int ldo,
    const float* __restrict__ bias, const float* __restrict__ resid) {
  __shared__ unsigned short As[BM * BK];
  __shared__ unsigned short Bs[BN * BK];
  const int t = threadIdx.x;
  const int w = t >> 6, l = t & 63;
  const int wm = w & 1, wn = w >> 1;
  const int q = l >> 4, ln = l & 15;

  const int L = blockIdx.y * 16 + blockIdx.x;
  const int xcd = L & 7;
  const int W = L >> 3;
  const int bx = W & 15;
  const int by = (W >> 4) * 8 + xcd;
  const int m0 = by * BM, n0 = bx * BN;

  f32x4 acc[4][4];
#pragma unroll
  for (int i = 0; i < 4; ++i)
#pragma unroll
    for (int j = 0; j < 4; ++j) acc[i][j] = {0.f, 0.f, 0.f, 0.f};

  for (int k0 = 0; k0 < K; k0 += BK) {
    __syncthreads();
#pragma unroll
    for (int r = 0; r < 4; ++r) {
      int s = r * 256 + t;
      int row = s >> 3;
      int ch = (s & 7) ^ (row & 7);
      const unsigned short* ga = A + (size_t)(m0 + row) * lda + k0 + ch * 8;
      __builtin_amdgcn_global_load_lds(
          (const __attribute__((address_space(1))) void*)ga,
          (__attribute__((address_space(3))) void*)(As + (r * 256 + w * 64) * 8), 16, 0, 0);
      const unsigned short* gb = Bt + (size_t)(n0 + row) * ldb + k0 + ch * 8;
      __builtin_amdgcn_global_load_lds(
          (const __attribute__((address_space(1))) void*)gb,
          (__attribute__((address_space(3))) void*)(Bs + (r * 256 + w * 64) * 8), 16, 0, 0);
    }
    __syncthreads();
#pragma unroll
    for (int h = 0; h < 2; ++h) {
      bf16x8 af[4], bfr[4];
#pragma unroll
      for (int mt = 0; mt < 4; ++mt) {
        int ar = wm * 64 + mt * 16 + ln;
        af[mt] = *(const bf16x8*)&As[ar * BK + (((h * 4 + q) ^ (ar & 7)) * 8)];
      }
#pragma unroll
      for (int nt = 0; nt < 4; ++nt) {
        int br = wn * 64 + nt * 16 + ln;
        bfr[nt] = *(const bf16x8*)&Bs[br * BK + (((h * 4 + q) ^ (br & 7)) * 8)];
      }
#pragma unroll
      for (int mt = 0; mt < 4; ++mt)
#pragma unroll
        for (int nt = 0; nt < 4; ++nt)
          acc[mt][nt] = __builtin_amdgcn_mfma_f32_16x16x32_bf16(af[mt], bfr[nt], acc[mt][nt], 0, 0, 0);
    }
  }

#pragma unroll
  for (int mt = 0; mt < 4; ++mt) {
#pragma unroll
    for (int i = 0; i < 4; ++i) {
      int row = m0 + wm * 64 + mt * 16 + q * 4 + i;
#pragma unroll
      for (int nt = 0; nt < 4; ++nt) {
        int col = n0 + wn * 64 + nt * 16 + ln;
        float vv = acc[mt][nt][i];
        if (MODE == 2) { vv += bias[(size_t)(row >> 11) * 2048 + col]; vv = fmaxf(vv, 0.f); }
        if (MODE == 4) {
          vv += bias[col]; vv = fmaxf(vv, 0.f);
          vv += resid[(size_t)row * 2048 + col];
          ((float*)outp)[(size_t)row * ldo + col] = vv;
        } else {
          ((unsigned short*)outp)[(size_t)row * ldo + col] = f2bf(vv);
        }
      }
    }
  }
}

// ============================================================================
// 256x256 8-phase GEMM (R1/R5 schedule; R7 = builtin s_barrier, no "memory"
// clobber). A/B ledger: vmcnt(8) schedule = 127-130us / 46-47% MfmaUtil;
// vmcnt(6) variants regressed (34-36%). R7 theory: asm barrier's "memory"
// clobber fenced every phase -> no cross-phase ds_read/MFMA overlap; the
// builtin (HK/m201's form) lets the compiler schedule across barriers.
// VMW asm keeps its clobber (2/tile, pins the staging ring).
// ============================================================================
#define GLD16(g, s)                                                        \
  __builtin_amdgcn_global_load_lds(                                        \
      (const __attribute__((address_space(1))) void*)(g),                  \
      (__attribute__((address_space(3))) void*)(s), 16, 0, 0)
#define BARX() __builtin_amdgcn_s_barrier()
#define VMW8() asm volatile("s_waitcnt vmcnt(8)" ::: "memory")
#define VMW4() asm volatile("s_waitcnt vmcnt(4)" ::: "memory")
#define VMW0() asm volatile("s_waitcnt vmcnt(0)" ::: "memory")

template <int MODE>
__global__ __launch_bounds__(512, 2) void gemm256_kernel(
    const unsigned short* __restrict__ A, int lda,
    const unsigned short* __restrict__ Bt, int ldb, int K,
    void* __restrict__ outp, int ldo,
    const float* __restrict__ bias, const float* __restrict__ resid) {
  __shared__ unsigned short As[2][2][256 * 32];
  __shared__ unsigned short Bs[2][2][256 * 32];
  const int t = threadIdx.x;
  const int wv = t >> 6, l = t & 63;
  const int wm = wv >> 2, wn = wv & 3;   // 2 x 4 wave grid
  const int q = l >> 4, ln = l & 15;

  const int L = blockIdx.y * 8 + blockIdx.x;
  const int lin = (L & 7) * 32 + (L >> 3);
  const int m0 = (lin >> 3) * 256, n0 = (lin & 7) * 256;

  const int srow = t >> 2;                                    // 0..127
  const int scol = (((t & 3) * 16) ^ (((srow >> 1) & 3) << 4)) >> 1;  // elems
  const unsigned short* Abase = A + (size_t)(m0 + srow) * lda + scol;
  const unsigned short* Bbase = Bt + (size_t)(n0 + srow) * ldb + scol;
  const size_t astep = (size_t)128 * lda, bstep = (size_t)128 * ldb;
  const int rsel = (q * 8) ^ (((ln >> 1) & 3) << 3);  // read swizzle (elems)

  f32x4 acc[8][4];
#pragma unroll
  for (int i = 0; i < 8; ++i)
#pragma unroll
    for (int j = 0; j < 4; ++j) acc[i][j] = {0.f, 0.f, 0.f, 0.f};

  auto stageA = [&](int kt, int kh, int buf) {
    const unsigned short* g = Abase + (size_t)kt * 64 + kh * 32;
    GLD16(g, &As[buf][kh][wv * 512]);
    GLD16(g + astep, &As[buf][kh][4096 + wv * 512]);
  };
  auto stageB = [&](int kt, int kh, int buf) {
    const unsigned short* g = Bbase + (size_t)kt * 64 + kh * 32;
    GLD16(g, &Bs[buf][kh][wv * 512]);
    GLD16(g + bstep, &Bs[buf][kh][4096 + wv * 512]);
  };

  bf16x8 a[8], b[2];
  auto loadA = [&](int buf, int h) {
#pragma unroll
    for (int mt = 0; mt < 8; ++mt) {
      int ar = wm * 128 + mt * 16 + ln;
      a[mt] = *(const bf16x8*)&As[buf][h][ar * 32 + rsel];
    }
  };
  auto loadB2 = [&](int buf, int h, int np) {
#pragma unroll
    for (int i = 0; i < 2; ++i) {
      int br = wn * 64 + (np * 2 + i) * 16 + ln;
      b[i] = *(const bf16x8*)&Bs[buf][h][br * 32 + rsel];
    }
  };
  auto mm = [&](int np) {
    __builtin_amdgcn_s_setprio(1);
#pragma unroll
    for (int mt = 0; mt < 8; ++mt)
#pragma unroll
      for (int i = 0; i < 2; ++i)
        acc[mt][np * 2 + i] =
            __builtin_amdgcn_mfma_f32_16x16x32_bf16(a[mt], b[i], acc[mt][np * 2 + i], 0, 0, 0);
    __builtin_amdgcn_s_setprio(0);
  };

  const int NT = K >> 6;
  stageA(0, 0, 0); stageB(0, 0, 0);
  stageA(0, 1, 0); stageB(0, 1, 0);
  stageA(1, 0, 1); stageB(1, 0, 1);
  VMW4();
  BARX();

  for (int tt = 0; tt < NT; ++tt) {
    const int c = tt & 1;
    const int t1 = (tt + 1 == NT) ? 0 : tt + 1;
    const int t2 = (tt + 2 >= NT) ? tt + 2 - NT : tt + 2;
    // ---- phase 1: kh0, nt{0,1} ----
    loadA(c, 0); loadB2(c, 0, 0);
    stageA(t1, 1, c ^ 1);
    BARX();
    mm(0);
    BARX();
    // ---- phase 2: kh0, nt{2,3} ----
    loadB2(c, 0, 1);
    stageB(t1, 1, c ^ 1);
    BARX();
    mm(1);
    VMW8();
    BARX();
    // ---- phase 3: kh1, nt{0,1} ----
    loadA(c, 1); loadB2(c, 1, 0);
    stageA(t2, 0, c);
    BARX();
    mm(0);
    BARX();
    // ---- phase 4: kh1, nt{2,3} ----
    loadB2(c, 1, 1);
    stageB(t2, 0, c);
    BARX();
    mm(1);
    VMW8();
    BARX();
  }
  VMW0();

#pragma unroll
  for (int mt = 0; mt < 8; ++mt) {
#pragma unroll
    for (int i = 0; i < 4; ++i) {
      int row = m0 + wm * 128 + mt * 16 + q * 4 + i;
#pragma unroll
      for (int nt = 0; nt < 4; ++nt) {
        int col = n0 + wn * 64 + nt * 16 + ln;
        float vv = acc[mt][nt][i];
        if (MODE == 2) { vv += bias[(size_t)(row >> 11) * 2048 + col]; vv = fmaxf(vv, 0.f); }
        if (MODE == 4) {
          vv += bias[col]; vv = fmaxf(vv, 0.f);
          vv += resid[(size_t)row * 2048 + col];
          ((float*)outp)[(size_t)row * ldo + col] = vv;
        } else {
          ((unsigned short*)outp)[(size_t)row * ldo + col] = f2bf(vv);
        }
      }
    }
  }
}

// ---- chunked scan over S of v[b][s][c] -- vectorized uint4 (8 bf16/lane) ----
__global__ __launch_bounds__(256) void scan_partial_kernel(
    const unsigned short* __restrict__ v, float* __restrict__ csum) {
  int chunk = blockIdx.x, b = blockIdx.y;
  int c0 = threadIdx.x * 8;
  const unsigned short* p = v + ((size_t)(b * S_DIM + chunk * CHLEN)) * D_DIM + c0;
  float s[8];
#pragma unroll
  for (int j = 0; j < 8; ++j) s[j] = 0.f;
  for (int i = 0; i < CHLEN; ++i) {
    uint4 u = *(const uint4*)(p + (size_t)i * D_DIM);
    s[0] += bfLo(u.x); s[1] += bfHi(u.x);
    s[2] += bfLo(u.y); s[3] += bfHi(u.y);
    s[4] += bfLo(u.z); s[5] += bfHi(u.z);
    s[6] += bfLo(u.w); s[7] += bfHi(u.w);
  }
  float* cs = csum + ((size_t)b * NCHUNK + chunk) * D_DIM + c0;
  float4 o0 = {s[0], s[1], s[2], s[3]}, o1 = {s[4], s[5], s[6], s[7]};
  *(float4*)cs = o0;
  *(float4*)(cs + 4) = o1;
}

// pooled into concat[:, 2048:4096]; own chunk-prefix from csum partials.
__global__ __launch_bounds__(256) void scan_apply_kernel(
    const unsigned short* __restrict__ v, const float* __restrict__ csum,
    const float* __restrict__ coef, unsigned short* __restrict__ pooled_out) {
  int chunk = blockIdx.x, b = blockIdx.y;
  int c0 = threadIdx.x * 8;
  const float* cs = csum + (size_t)b * NCHUNK * D_DIM + c0;
  float run[8];
#pragma unroll
  for (int j = 0; j < 8; ++j) run[j] = 0.f;
  for (int j = 0; j < chunk; ++j) {
    float4 a = *(const float4*)(cs + (size_t)j * D_DIM);
    float4 d = *(const float4*)(cs + (size_t)j * D_DIM + 4);
    run[0] += a.x; run[1] += a.y; run[2] += a.z; run[3] += a.w;
    run[4] += d.x; run[5] += d.y; run[6] += d.z; run[7] += d.w;
  }
  int row0 = b * S_DIM + chunk * CHLEN;
  const unsigned short* vp = v + (size_t)row0 * D_DIM + c0;
  unsigned short* po = pooled_out + (size_t)row0 * CONCAT_LD + c0;
  const float* cf = coef + (size_t)row0 * H_DIM + (c0 >> 7);
  for (int i = 0; i < CHLEN; ++i) {
    uint4 u = *(const uint4*)(vp + (size_t)i * D_DIM);
    run[0] += bfLo(u.x); run[1] += bfHi(u.x);
    run[2] += bfLo(u.y); run[3] += bfHi(u.y);
    run[4] += bfLo(u.z); run[5] += bfHi(u.z);
    run[6] += bfLo(u.w); run[7] += bfHi(u.w);
    float cv = cf[(size_t)i * H_DIM];
    uint4 o;
    o.x = (unsigned)f2bf(cv * run[0]) | ((unsigned)f2bf(cv * run[1]) << 16);
    o.y = (unsigned)f2bf(cv * run[2]) | ((unsigned)f2bf(cv * run[3]) << 16);
    o.z = (unsigned)f2bf(cv * run[4]) | ((unsigned)f2bf(cv * run[5]) << 16);
    o.w = (unsigned)f2bf(cv * run[6]) | ((unsigned)f2bf(cv * run[7]) << 16);
    *(uint4*)(po + (size_t)i * CONCAT_LD) = o;
  }
}

// ---- in-place LayerNorm on d_out rows (float4 loads/stores) ----
__global__ __launch_bounds__(256) void ln_kernel(
    float* __restrict__ out, const float* __restrict__ gamma, const float* __restrict__ beta) {
  int row = blockIdx.x, t = threadIdx.x;
  float* pr = out + (size_t)row * D_DIM;
  int c = t * 4;
  float4 va = *(const float4*)(pr + c);
  float4 vb = *(const float4*)(pr + c + 1024);
  float s = va.x + va.y + va.z + va.w + vb.x + vb.y + vb.z + vb.w;
  __shared__ float red[4];
  for (int off = 32; off; off >>= 1) s += __shfl_down(s, off);
  if ((t & 63) == 0) red[t >> 6] = s;
  __syncthreads();
  float mean = (red[0] + red[1] + red[2] + red[3]) * (1.f / D_DIM);
  __syncthreads();
  float c2 = 0.f;
  {
    float d;
    d = va.x - mean; c2 += d * d; d = va.y - mean; c2 += d * d;
    d = va.z - mean; c2 += d * d; d = va.w - mean; c2 += d * d;
    d = vb.x - mean; c2 += d * d; d = vb.y - mean; c2 += d * d;
    d = vb.z - mean; c2 += d * d; d = vb.w - mean; c2 += d * d;
  }
  for (int off = 32; off; off >>= 1) c2 += __shfl_down(c2, off);
  if ((t & 63) == 0) red[t >> 6] = c2;
  __syncthreads();
  float var = (red[0] + red[1] + red[2] + red[3]) * (1.f / D_DIM);
  float rstd = rsqrtf(var + 1e-6f);
  float4 ga = *(const float4*)(gamma + c), ba = *(const float4*)(beta + c);
  float4 gb = *(const float4*)(gamma + c + 1024), bb = *(const float4*)(beta + c + 1024);
  float4 oa, ob;
  oa.x = (va.x - mean) * rstd * ga.x + ba.x;
  oa.y = (va.y - mean) * rstd * ga.y + ba.y;
  oa.z = (va.z - mean) * rstd * ga.z + ba.z;
  oa.w = (va.w - mean) * rstd * ga.w + ba.w;
  ob.x = (vb.x - mean) * rstd * gb.x + bb.x;
  ob.y = (vb.y - mean) * rstd * gb.y + bb.y;
  ob.z = (vb.z - mean) * rstd * gb.z + bb.z;
  ob.w = (vb.w - mean) * rstd * gb.w + bb.w;
  *(float4*)(pr + c) = oa;
  *(float4*)(pr + c + 1024) = ob;
}

extern "C" void kernel_launch(void* const* d_in, const int* in_sizes, int n_in,
                              void* d_out, int out_size, void* d_ws, size_t ws_size,
                              hipStream_t stream) {
  const float* x      = (const float*)d_in[0];
  const float* vector = (const float*)d_in[1];
  const float* W_att  = (const float*)d_in[2];
  const float* temp   = (const float*)d_in[3];
  const float* W_val  = (const float*)d_in[4];
  const float* W_op   = (const float*)d_in[5];
  const float* ff1    = (const float*)d_in[6];
  const float* ff1_b  = (const float*)d_in[7];
  const float* ff2    = (const float*)d_in[8];
  const float* ff2_b  = (const float*)d_in[9];
  const float* gamma  = (const float*)d_in[10];
  const float* beta   = (const float*)d_in[11];
  float* out = (float*)d_out;

  char* ws = (char*)d_ws;
  auto alloc = [&](size_t bytes) {
    char* p = ws; ws += (bytes + 255) & ~(size_t)255; return p;
  };
  unsigned short* concat = (unsigned short*)alloc((size_t)M_ROWS * CONCAT_LD * 2);  // [x | pooled]
  unsigned short* wv_t   = (unsigned short*)alloc((size_t)2048 * 2048 * 2);
  unsigned short* btff1  = (unsigned short*)alloc((size_t)2048 * 4096 * 2);  // [F1a^T | Wc^T] rows n, ld 4096
  unsigned short* f1bT   = (unsigned short*)alloc((size_t)2048 * 2048 * 2);
  unsigned short* wop_bf = (unsigned short*)alloc((size_t)2048 * 2048 * 2);
  unsigned short* ff2_t  = (unsigned short*)alloc((size_t)2048 * 2048 * 2);
  unsigned short* vbuf   = (unsigned short*)alloc((size_t)M_ROWS * 2048 * 2);
  unsigned short* h1     = (unsigned short*)alloc((size_t)M_ROWS * 2048 * 2);
  float* logits = (float*)alloc((size_t)M_ROWS * H_DIM * 4);
  float* coef   = (float*)alloc((size_t)M_ROWS * H_DIM * 4);
  float* csum   = (float*)alloc((size_t)B_DIM * NCHUNK * D_DIM * 4);
  float* part   = (float*)alloc((size_t)16 * 4 * 2048 * 4);
  float* bias2  = (float*)alloc((size_t)4 * 2048 * 4);

  prep_kernel<<<dim3(64, 32, 5), 256, 0, stream>>>(
      W_val, ff1, ff2, W_op, wv_t, btff1, f1bT, ff2_t, wop_bf);
  xconv_logits_kernel<<<M_ROWS / 4, 256, 0, stream>>>(x, W_att, concat, logits);
  coef_kernel<<<B_DIM * H_DIM, 256, 0, stream>>>(logits, temp, coef);
  // Wc^T[n][i] = (F1b^T @ W_op^T)[n][i] -> btff1[:, 2048:4096]
  gemm_bt_kernel<1><<<dim3(16, 16), 256, 0, stream>>>(
      f1bT, 2048, wop_bf, 2048, 2048, btff1 + 2048, 4096, nullptr, nullptr);
  // bias2 = vector @ F1b + ff1_b
  bias2_partial_kernel<<<dim3(8, 16, 4), 256, 0, stream>>>(vector, ff1, part);
  bias2_reduce_kernel<<<dim3(8, 4), 256, 0, stream>>>(part, ff1_b, bias2);
  // v = x @ W_values
  gemm256_kernel<1><<<dim3(8, 32), 512, 0, stream>>>(
      concat, CONCAT_LD, wv_t, 2048, 2048, vbuf, 2048, nullptr, nullptr);
  scan_partial_kernel<<<dim3(NCHUNK, B_DIM), 256, 0, stream>>>(vbuf, csum);
  scan_apply_kernel<<<dim3(NCHUNK, B_DIM), 256, 0, stream>>>(vbuf, csum, coef, concat + 2048);
  // h1 = relu([x|pooled] @ [F1a;Wc] + bias2[b])   (K=4096)
  gemm256_kernel<2><<<dim3(8, 32), 512, 0, stream>>>(
      concat, CONCAT_LD, btff1, 4096, 4096, h1, 2048, bias2, nullptr);
  // out = relu(h1 @ ff2 + ff2_b) + x
  gemm256_kernel<4><<<dim3(8, 32), 512, 0, stream>>>(
      h1, 2048, ff2_t, 2048, 2048, out, 2048, ff2_b, x);
  ln_kernel<<<M_ROWS, 256, 0, stream>>>(out, gamma, beta);
}